// Round 5
// baseline (3167.467 us; speedup 1.0000x reference)
//
#include <hip/hip_runtime.h>
#include <math.h>

// MD-LSTM, 32x32 grid, B=128, HID=256, gates=1024.
// Diagonal wavefront: 63 launches; cells on diag d depend only on diag d-1.
//
// ACCURACY: whole recurrence in fp64 (fp32 trajectories diverge past the
// 1.945e-2 threshold). GEMM on v_mfma_f64_16x16x4f64; D-fragment layout
// probed at runtime (R2 passed => probe resolves correctly on HW).
//
// R3 post-mortem: cooperative/persistent path = 262us/diagonal (per-thread
// __threadfence => ~4096 L2-writeback cmds/diag + grid.sync spin) — dead
// end; the CP's per-dispatch flush is cheaper than any software barrier
// here. Timed path fell back to 63 launches (3112us). R3's profile also
// exposed SQ_LDS_BANK_CONFLICT=3.35e8 for this inner code: the W staging
// write W[(4kq+e)*136+phi] has bank=(8e+phi)%32 -> 8-way conflict.
//
// R4 (re-run; R4 bench was an infra failure, kernel never executed):
//  1. W_lds layout [k][136] -> [phi][36]: staging = 1 ds_write_b128/p
//     (bank pattern 4(phi+kq)+e is exactly uniform = conflict-free);
//     MFMA B reads bank=(4cc+gg)%32 = 2-way = free.
//  2. XCD A-locality: the 8 ktile-blocks of group g=(cell,b4) read the
//     SAME 524KB A-panel; old id%8=ktile spread them over 8 XCDs (8x
//     replicated L2-miss traffic). New mapping gives them id%8 = g%8
//     (same XCD): id = (g%8) + 8*((g/8)*8 + ktile), grid padded to
//     ceil(4nc/8)*64, excess blocks exit. A-panel hits one L2 once.
//  3. Epilogue operands (x, s_up, s_left) prefetched before G-scatter.
//
// LDS (32 KB, unioned):
//   stage: A[k=32][rotRow=32] f64 (rot (row+k)&31, conflict-free)
//          W[phi=128][36] f32 (+4 pad)
//   gates: G[phi=128][rot 32] f64 after the K-loop.

#define HIMG 32
#define WIMG 32
#define BATCH 128
#define HID 256
#define BH (BATCH * HID)
#define SLAB (32 * 128 * 256)

#define PSTR 36  // floats per phi-row of W_lds (32 + 4 pad)

typedef double f64x4 __attribute__((ext_vector_type(4)));

__global__ __launch_bounds__(256, 4)
void mdlstm_diag_kernel(const float* __restrict__ x,
                        const float* __restrict__ wih,
                        const float* __restrict__ whh,
                        const float* __restrict__ bias,
                        float* __restrict__ out,
                        double* __restrict__ hbuf,   // [2][32][128][256]
                        double* __restrict__ sbuf,   // [2][32][128][256]
                        int d, int rlo, int nc)
{
    __shared__ double lds[4096];             // 32 KB
    double* A_lds = lds;                     // [k=32][rot=32]     8 KB
    float*  W_lds = (float*)(lds + 1024);    // [phi=128][PSTR=36] 18 KB
    double* G_lds = lds;                     // [phi=128][rot=32]  32 KB

    const int tid = threadIdx.x;
    const int id  = blockIdx.x;

    // ---- XCD-locality decode: id = (g%8) + 8*((g/8)*8 + ktile) ----
    const int rx    = id & 7;
    const int q     = id >> 3;
    const int ktile = q & 7;
    const int ghi   = q >> 3;
    const int g     = ghi * 8 + rx;          // group = cell*4 + b4
    if (g >= nc * 4) return;                 // padded grid tail
    const int cellIdx = g >> 2;
    const int b4      = g & 3;
    const int k0 = ktile * 32;
    const int b0 = b4 * 32;

    const int r = rlo + cellIdx;
    const int c = d - r;
    const int rc = r * WIMG + c;

    const int prev = (d & 1) ^ 1;
    const int cur  = d & 1;
    const double* hp = hbuf + (size_t)prev * SLAB;
    const double* sp = sbuf + (size_t)prev * SLAB;
    double* hc = hbuf + (size_t)cur * SLAB;
    double* sc = sbuf + (size_t)cur * SLAB;

    const bool has_up   = (r > 0);
    const bool has_left = (c > 0);
    const double* hu = hp + (size_t)(r - 1) * BH;  // valid iff has_up
    const double* hl = hp + (size_t)r * BH;        // valid iff has_left

    // ---- wave / lane geometry ----
    const int lane = tid & 63;
    const int wid  = tid >> 6;
    const int wb0  = (wid & 1) * 16;         // wave's batch offset in block
    const int wf0  = (wid >> 1) * 64;        // wave's phi offset in block
    const int cc   = lane & 15;
    const int gg   = lane >> 4;

    // ---- D-layout probe (one MFMA; distinguishes 4 candidate mappings) ----
    int layout;
    {
        double pa = (cc == 1) ? 1.0 : 0.0;
        double pb = (cc == 2) ? 1.0 : 0.0;
        f64x4 pc = {0.0, 0.0, 0.0, 0.0};
        pc = __builtin_amdgcn_mfma_f64_16x16x4f64(pa, pb, pc, 0, 0, 0);
        double s = fabs(pc[0]) + fabs(pc[1]) + fabs(pc[2]) + fabs(pc[3]);
        #pragma unroll
        for (int off = 32; off > 0; off >>= 1) s += __shfl_xor(s, off, 64);
        unsigned long long h0 = __ballot(lane == 2  && pc[1] == 4.0);
        unsigned long long h1 = __ballot(lane == 18 && pc[0] == 4.0);
        unsigned long long h2 = __ballot(lane == 1  && pc[2] == 4.0);
        unsigned long long h3 = __ballot(lane == 33 && pc[0] == 4.0);
        layout = -1;
        if (s == 4.0) {
            if (h0) layout = 0;
            else if (h1) layout = 1;
            else if (h2) layout = 2;
            else if (h3) layout = 3;
        }
    }
    const bool use_mfma = (layout >= 0);

    // ---- staging maps ----
    const int a_row = tid >> 4;
    const int a_kp  = tid & 15;
    const size_t ga0 = (size_t)(b0 + a_row) * HID + 2 * a_kp;
    const size_t ga1 = ga0 + (size_t)16 * HID;
    // W: p in 0..3: u=tid+p*256; phi=u>>3 (0..127), kq=u&7; float4 along k.
    const float* w_src[4];
    int w_pos[4];
    #pragma unroll
    for (int p = 0; p < 4; p++) {
        int u = tid + p * 256;
        int phi = u >> 3, kq = u & 7;
        int F = (phi >> 5) * 256 + k0 + (phi & 31);   // global gate row
        w_src[p] = whh + (size_t)F * HID + 4 * kq;
        w_pos[p] = phi * PSTR + 4 * kq;               // LDS float index
    }

    f64x4 acc[4];
    #pragma unroll
    for (int ft = 0; ft < 4; ft++) acc[ft] = (f64x4){0.0, 0.0, 0.0, 0.0};

    // ---- prefetch chunk 0 ----
    double2 pu0, pu1, pl0, pl1;
    float4 pw[4];
    {
        const double2 z = {0.0, 0.0};
        pu0 = has_up   ? *(const double2*)(hu + ga0) : z;
        pu1 = has_up   ? *(const double2*)(hu + ga1) : z;
        pl0 = has_left ? *(const double2*)(hl + ga0) : z;
        pl1 = has_left ? *(const double2*)(hl + ga1) : z;
        #pragma unroll
        for (int p = 0; p < 4; p++)
            pw[p] = *(const float4*)(w_src[p]);
    }

    const float* wbase = &W_lds[(wf0 + cc) * PSTR + gg];

    for (int ck = 0; ck < 8; ck++) {
        __syncthreads();                  // previous compute done reading LDS
        {
            const int k = 2 * a_kp;
            const double s0x = pu0.x + pl0.x, s0y = pu0.y + pl0.y;
            const double s1x = pu1.x + pl1.x, s1y = pu1.y + pl1.y;
            A_lds[ k      * 32 + ((a_row      + k    ) & 31)] = s0x;
            A_lds[(k + 1) * 32 + ((a_row      + k + 1) & 31)] = s0y;
            A_lds[ k      * 32 + ((a_row + 16 + k    ) & 31)] = s1x;
            A_lds[(k + 1) * 32 + ((a_row + 16 + k + 1) & 31)] = s1y;
        }
        #pragma unroll
        for (int p = 0; p < 4; p++)
            *(float4*)&W_lds[w_pos[p]] = pw[p];   // b128, conflict-free
        __syncthreads();                  // LDS ready

        if (ck < 7) {                     // prefetch next chunk during compute
            const int kg = (ck + 1) * 32;
            const double2 z = {0.0, 0.0};
            pu0 = has_up   ? *(const double2*)(hu + ga0 + kg) : z;
            pu1 = has_up   ? *(const double2*)(hu + ga1 + kg) : z;
            pl0 = has_left ? *(const double2*)(hl + ga0 + kg) : z;
            pl1 = has_left ? *(const double2*)(hl + ga1 + kg) : z;
            #pragma unroll
            for (int p = 0; p < 4; p++)
                pw[p] = *(const float4*)(w_src[p] + kg);
        }

        if (use_mfma) {
            // ---- MFMA inner loop: 8 k-steps x 4 f-tiles ----
            #pragma unroll
            for (int t = 0; t < 8; t++) {
                const int kq = t * 4 + gg;
                const double aval = A_lds[kq * 32 + ((wb0 + cc + kq) & 31)];
                #pragma unroll
                for (int ft = 0; ft < 4; ft++) {
                    const double bval = (double)wbase[ft * (16 * PSTR) + 4 * t];
                    acc[ft] = __builtin_amdgcn_mfma_f64_16x16x4f64(aval, bval, acc[ft], 0, 0, 0);
                }
            }
        } else {
            // ---- VALU fallback (row=wb0+4*gg+b, col=cc) ----
            for (int k = 0; k < 32; k++) {
                double av[4], wv4[4];
                #pragma unroll
                for (int b = 0; b < 4; b++)
                    av[b] = A_lds[k * 32 + ((wb0 + 4 * gg + b + k) & 31)];
                #pragma unroll
                for (int ft = 0; ft < 4; ft++)
                    wv4[ft] = (double)W_lds[(wf0 + ft * 16 + cc) * PSTR + k];
                #pragma unroll
                for (int ft = 0; ft < 4; ft++)
                    #pragma unroll
                    for (int b = 0; b < 4; b++)
                        acc[ft][b] = fma(av[b], wv4[ft], acc[ft][b]);
            }
        }
    }

    // ---- epilogue operand prefetch (hides under G scatter) ----
    const int ec = tid & 31;
    const int eb = tid >> 5;
    const int kE = k0 + ec;
    double xp4[4], su4[4], sl4[4];
    #pragma unroll
    for (int i = 0; i < 4; i++) {
        const int b = b0 + eb + 8 * i;
        xp4[i] = (double)x[b * (HIMG * WIMG) + rc];
        su4[i] = has_up   ? sp[(size_t)(r - 1) * BH + b * HID + kE] : 0.0;
        sl4[i] = has_left ? sp[(size_t)r * BH + b * HID + kE]       : 0.0;
    }

    // ---- gates -> LDS (layout-generic D-frag scatter; rot swizzle) ----
    __syncthreads();                      // done reading stage LDS
    const int slay = use_mfma ? layout : 0;
    #pragma unroll
    for (int ft = 0; ft < 4; ft++) {
        #pragma unroll
        for (int b = 0; b < 4; b++) {
            const int rA = (slay & 1) ? (gg + 4 * b) : (4 * gg + b);
            const int m  = (slay >= 2) ? cc : rA;   // local batch row
            const int n  = (slay >= 2) ? rA : cc;   // local phi
            const int phi  = wf0 + ft * 16 + n;
            const int brow = wb0 + m;
            G_lds[phi * 32 + ((brow + phi) & 31)] = acc[ft][b];
        }
    }
    __syncthreads();

    // ---- fused epilogue (all fp64) ----
    double wv[4], bv[4];
    #pragma unroll
    for (int g2 = 0; g2 < 4; g2++) {
        wv[g2] = (double)wih[g2 * 256 + kE];
        bv[g2] = (double)bias[g2 * 256 + kE];
    }
    #pragma unroll
    for (int i = 0; i < 4; i++) {
        const int bl = eb + 8 * i;
        const int b = b0 + bl;
        double gate[4];
        #pragma unroll
        for (int g2 = 0; g2 < 4; g2++) {
            const int phi = g2 * 32 + ec;
            gate[g2] = G_lds[phi * 32 + ((bl + phi) & 31)];
        }
        const double gi = gate[0] + xp4[i] * wv[0] + bv[0];
        const double gf = gate[1] + xp4[i] * wv[1] + bv[1];
        const double gG = gate[2] + xp4[i] * wv[2] + bv[2];
        const double go = gate[3] + xp4[i] * wv[3] + bv[3];
        const double iv = 1.0 / (1.0 + exp(-gi));
        const double fv = 1.0 / (1.0 + exp(-gf));
        const double gv = tanh(gG);
        const double ov = 1.0 / (1.0 + exp(-go));
        const double sv = fv * (su4[i] + sl4[i]) + iv * gv;
        const double hv = ov * tanh(sv);
        sc[(size_t)r * BH + b * HID + kE] = sv;
        hc[(size_t)r * BH + b * HID + kE] = hv;
        out[(size_t)b * (HIMG * WIMG * HID) + (size_t)rc * HID + kE] = (float)hv;
    }
}

extern "C" void kernel_launch(void* const* d_in, const int* in_sizes, int n_in,
                              void* d_out, int out_size, void* d_ws, size_t ws_size,
                              hipStream_t stream) {
    const float* x    = (const float*)d_in[0];   // (128, 1024)
    const float* wih  = (const float*)d_in[1];   // (1024, 1)
    const float* whh  = (const float*)d_in[2];   // (1024, 256)
    const float* bias = (const float*)d_in[3];   // (1024,)
    float* out = (float*)d_out;                  // (128, 32*32*256)

    double* hbuf = (double*)d_ws;                // [2][32][128][256] dbl
    double* sbuf = hbuf + (size_t)2 * SLAB;      // ws usage ~33.6 MB

    for (int d = 0; d < HIMG + WIMG - 1; d++) {
        int rlo = d - (WIMG - 1); if (rlo < 0) rlo = 0;
        int rhi = d < (HIMG - 1) ? d : (HIMG - 1);
        int nc = rhi - rlo + 1;
        int g8 = (4 * nc + 7) / 8;               // padded group-octets
        mdlstm_diag_kernel<<<dim3(g8 * 64), 256, 0, stream>>>(
            x, wih, whh, bias, out, hbuf, sbuf, d, rlo, nc);
    }
}